// Round 3
// baseline (408.351 us; speedup 1.0000x reference)
//
#include <hip/hip_runtime.h>
#include <stdint.h>

typedef short short8 __attribute__((ext_vector_type(8)));
typedef float f32x4 __attribute__((ext_vector_type(4)));

// 0.125 (1/sqrt(64)) * log2(e): fold softmax scale + exp2-domain into Q.
#define QSCALE 0.1803368801111137f
// log2(10000)/32
#define FREQC 0.4152410118609203f

__device__ __forceinline__ float bf2f(unsigned short u) {
    union { unsigned int i; float f; } x; x.i = ((unsigned int)u) << 16; return x.f;
}
__device__ __forceinline__ unsigned short f2bf(float f) {
    union { float f; unsigned int i; } x; x.f = f;
    unsigned int i = x.i;
    unsigned int r = i + 0x7FFFu + ((i >> 16) & 1u);   // RNE
    return (unsigned short)(r >> 16);
}

// async global->LDS, 16B/lane. HW dest = wave-uniform base + lane*16.
#define GLDS16(g, l) \
    __builtin_amdgcn_global_load_lds((const __attribute__((address_space(1))) void*)(g), \
                                     (__attribute__((address_space(3))) void*)(l), 16, 0, 0)

// ---------------- fused fp32 -> bf16 convert for all 4 arrays ----------------
__global__ void cvt_all(const float* __restrict__ hs, const float* __restrict__ k,
                        const float* __restrict__ wq, const float* __restrict__ wo,
                        unsigned short* __restrict__ hs_b, unsigned short* __restrict__ k_b,
                        unsigned short* __restrict__ wq_b, unsigned short* __restrict__ wo_b) {
    int blk = blockIdx.x;
    const float* in; unsigned short* out; int i;
    if (blk < 8192)        { in = hs; out = hs_b; i = blk * 256 + threadIdx.x; }
    else if (blk < 16384)  { in = k;  out = k_b;  i = (blk - 8192) * 256 + threadIdx.x; }
    else if (blk < 20480)  { in = wq; out = wq_b; i = (blk - 16384) * 256 + threadIdx.x; }
    else                   { in = wo; out = wo_b; i = (blk - 20480) * 256 + threadIdx.x; }
    float4 v = ((const float4*)in)[i];
    ushort4 o;
    o.x = f2bf(v.x); o.y = f2bf(v.y); o.z = f2bf(v.z); o.w = f2bf(v.w);
    ((ushort4*)out)[i] = o;
}

// ---------------- V: (B,T,H,D) f32 -> (B,H,D,T) bf16 ----------------
__global__ __launch_bounds__(256) void transpose_v(const float* __restrict__ V, unsigned short* __restrict__ Vt) {
    __shared__ float s[64 * 65];
    int t0 = blockIdx.x * 64;
    int bh = blockIdx.y;           // b*32 + h
    int b = bh >> 5, h = bh & 31;
    int tid = threadIdx.x;
#pragma unroll
    for (int it = 0; it < 4; ++it) {
        int c = tid + it * 256;
        int t = c >> 4;
        int d0 = (c & 15) * 4;
        float4 v = *(const float4*)(V + (size_t)(((b * 2048 + t0 + t) * 32 + h)) * 64 + d0);
        s[t * 65 + d0 + 0] = v.x; s[t * 65 + d0 + 1] = v.y;
        s[t * 65 + d0 + 2] = v.z; s[t * 65 + d0 + 3] = v.w;
    }
    __syncthreads();
#pragma unroll
    for (int it = 0; it < 2; ++it) {
        int c = tid + it * 256;
        int d = c >> 3;
        int tt = (c & 7) * 8;
        short8 pk;
#pragma unroll
        for (int j = 0; j < 8; ++j) pk[j] = (short)f2bf(s[(tt + j) * 65 + d]);
        *(short8*)(Vt + (size_t)(bh * 64 + d) * 2048 + t0 + tt) = pk;
    }
}

// ---------------- bf16 GEMM, C = A * B^T; BK=64, XOR-swizzled LDS ----------------
// 128x128 tile. Staging: wave w rows [32w,32w+32), 4 GLDS16 issues of 8 rows each;
// lane L -> row 8i+(L>>3), k-group (L&7)^(L>>3)  => chunk c=r*8+j holds k-group j^(r&7).
// Frag read chunk = R*8 + ((kk*4+q)^(R&7)): bank-quad spread 8-wide -> 2-way (free).
template <bool BF16_OUT>
__global__ __launch_bounds__(256) void gemm_bt(
    const unsigned short* __restrict__ A,   // M x K bf16
    const unsigned short* __restrict__ B,   // N x K bf16
    void* __restrict__ Cout,                // M x N
    int M, int N, int K)
{
    __shared__ __align__(16) unsigned short lA[128 * 64];
    __shared__ __align__(16) unsigned short lB[128 * 64];
    int tid = threadIdx.x, lane = tid & 63, wave = tid >> 6;
    int wm = (wave >> 1) * 64, wn = (wave & 1) * 64;
    int m16 = lane & 15, q = lane >> 4;
    int rowBase = blockIdx.x * 128, colBase = blockIdx.y * 128;
    f32x4 acc[4][4] = {};

    int sr = lane >> 3;            // 0..7: row within 8-row group
    int g  = (lane & 7) ^ sr;      // swizzled k-group
    const unsigned short* gAp = A + (size_t)(rowBase + wave * 32 + sr) * K + g * 8;
    const unsigned short* gBp = B + (size_t)(colBase + wave * 32 + sr) * K + g * 8;
    unsigned short* lAd = &lA[(wave * 32) * 64];
    unsigned short* lBd = &lB[(wave * 32) * 64];

    for (int k0 = 0; k0 < K; k0 += 64) {
        __syncthreads();
#pragma unroll
        for (int i = 0; i < 4; ++i) {
            GLDS16(gAp + (size_t)(8 * i) * K + k0, lAd + (8 * i) * 64);
            GLDS16(gBp + (size_t)(8 * i) * K + k0, lBd + (8 * i) * 64);
        }
        __syncthreads();
#pragma unroll
        for (int kk = 0; kk < 2; ++kk) {
            short8 af[4], bfr[4];
#pragma unroll
            for (int i = 0; i < 4; ++i) {
                int RA = wm + i * 16 + m16;
                af[i]  = *(const short8*)&lA[RA * 64 + (((kk * 4 + q) ^ (RA & 7)) * 8)];
                int RB = wn + i * 16 + m16;
                bfr[i] = *(const short8*)&lB[RB * 64 + (((kk * 4 + q) ^ (RB & 7)) * 8)];
            }
#pragma unroll
            for (int i = 0; i < 4; ++i)
#pragma unroll
                for (int jn = 0; jn < 4; ++jn)
                    acc[i][jn] = __builtin_amdgcn_mfma_f32_16x16x32_bf16(af[i], bfr[jn], acc[i][jn], 0, 0, 0);
        }
    }
#pragma unroll
    for (int i = 0; i < 4; ++i)
#pragma unroll
        for (int jn = 0; jn < 4; ++jn)
#pragma unroll
            for (int r = 0; r < 4; ++r) {
                int row = rowBase + wm + i * 16 + q * 4 + r;   // C row = quad*4+reg
                int col = colBase + wn + jn * 16 + m16;        // C col = lane&15
                float v = acc[i][jn][r];
                if (BF16_OUT) ((unsigned short*)Cout)[(size_t)row * N + col] = f2bf(v);
                else          ((float*)Cout)[(size_t)row * N + col] = v;
            }
}

// ---------------- flash attention (causal), paired Q-tiles, RoPE fused ----------------
// Block = (pair p, bh): Q-tiles qtA=31-p and qtB=p -> exactly 33 tile-computations
// per block (perfect balance), shared K/V staging (max(qtA,qtB)+1 = 32-p tiles).
// Grid 1024 = 4 blocks/CU resident (launch_bounds caps VGPR at 128).
// flat%8 == bh%8 -> all pairs of one (b,h) on one XCD for K/V L2 reuse.
__global__ __launch_bounds__(256, 4) void attn(
    const unsigned short* __restrict__ Q,   // (B*T) x 2048, raw gemm1 output (no rope)
    const unsigned short* __restrict__ Kb,  // (B*T) x 2048
    const unsigned short* __restrict__ Vt,  // (B*H*64) x 2048  (d-major)
    unsigned short* __restrict__ O)         // (B*T) x 2048
{
    const int SL = 72;  // stride 36 dwords -> 2-way bank aliasing only (free)
    __shared__ __align__(16) unsigned short sK[64 * SL];
    __shared__ __align__(16) unsigned short sV[64 * SL];     // rows = d, cols = key
    __shared__ __align__(16) unsigned short sP[4][16 * SL];
    int tid = threadIdx.x, lane = tid & 63, w = tid >> 6;
    int m16 = lane & 15, q = lane >> 4;
    int flat = blockIdx.x;
    int bh = flat & 63, p = flat >> 6;
    int b = bh >> 5, h = bh & 31;
    int qtA = 31 - p, qtB = p;

    // Q fragments for both tiles: load, RoPE (interleaved pairs are frag-local), scale.
    short8 aqA0, aqA1, aqB0, aqB1;
    {
        int tA = qtA * 64 + w * 16 + m16;
        int tB = qtB * 64 + w * 16 + m16;
        const unsigned short* rowA = Q + (size_t)(b * 2048 + tA) * 2048 + h * 64 + q * 8;
        const unsigned short* rowB = Q + (size_t)(b * 2048 + tB) * 2048 + h * 64 + q * 8;
        short8 a0 = *(const short8*)rowA, a1 = *(const short8*)(rowA + 32);
        short8 b0 = *(const short8*)rowB, b1 = *(const short8*)(rowB + 32);
        float tfA = (float)tA, tfB = (float)tB;
#pragma unroll
        for (int j = 0; j < 4; ++j) {
            float inv0 = __builtin_amdgcn_exp2f(-FREQC * (float)(q * 4 + j));
            float inv1 = __builtin_amdgcn_exp2f(-FREQC * (float)(16 + q * 4 + j));
            float cA0 = __cosf(tfA * inv0), sA0 = __sinf(tfA * inv0);
            float cA1 = __cosf(tfA * inv1), sA1 = __sinf(tfA * inv1);
            float cB0 = __cosf(tfB * inv0), sB0 = __sinf(tfB * inv0);
            float cB1 = __cosf(tfB * inv1), sB1 = __sinf(tfB * inv1);
            float x1, x2;
            x1 = bf2f((unsigned short)a0[2 * j]); x2 = bf2f((unsigned short)a0[2 * j + 1]);
            aqA0[2 * j]     = (short)f2bf((x1 * cA0 - x2 * sA0) * QSCALE);
            aqA0[2 * j + 1] = (short)f2bf((x1 * sA0 + x2 * cA0) * QSCALE);
            x1 = bf2f((unsigned short)a1[2 * j]); x2 = bf2f((unsigned short)a1[2 * j + 1]);
            aqA1[2 * j]     = (short)f2bf((x1 * cA1 - x2 * sA1) * QSCALE);
            aqA1[2 * j + 1] = (short)f2bf((x1 * sA1 + x2 * cA1) * QSCALE);
            x1 = bf2f((unsigned short)b0[2 * j]); x2 = bf2f((unsigned short)b0[2 * j + 1]);
            aqB0[2 * j]     = (short)f2bf((x1 * cB0 - x2 * sB0) * QSCALE);
            aqB0[2 * j + 1] = (short)f2bf((x1 * sB0 + x2 * cB0) * QSCALE);
            x1 = bf2f((unsigned short)b1[2 * j]); x2 = bf2f((unsigned short)b1[2 * j + 1]);
            aqB1[2 * j]     = (short)f2bf((x1 * cB1 - x2 * sB1) * QSCALE);
            aqB1[2 * j + 1] = (short)f2bf((x1 * sB1 + x2 * cB1) * QSCALE);
        }
    }

    float lrunA[4] = {0.f, 0.f, 0.f, 0.f}, lrunB[4] = {0.f, 0.f, 0.f, 0.f};
    f32x4 accOA[4], accOB[4];
#pragma unroll
    for (int nt = 0; nt < 4; ++nt) {
        f32x4 z = {0.f, 0.f, 0.f, 0.f};
        accOA[nt] = z; accOB[nt] = z;
    }

    int cK = tid >> 3, c8 = tid & 7;
    const unsigned short* kbase = Kb + (size_t)(b * 2048) * 2048 + h * 64;
    const unsigned short* vbase = Vt + (size_t)((b * 32 + h) * 64) * 2048;

    // one tile-computation: QK^T -> mask -> exp2 -> P (LDS round-trip) -> PV
    auto process = [&](short8 aq0, short8 aq1, float* lrun, f32x4* accO, int qt, int kt) {
        f32x4 accS[4];
#pragma unroll
        for (int nt = 0; nt < 4; ++nt) {
            f32x4 z = {0.f, 0.f, 0.f, 0.f};
            short8 bk0 = *(const short8*)&sK[(nt * 16 + m16) * SL + q * 8];
            short8 bk1 = *(const short8*)&sK[(nt * 16 + m16) * SL + 32 + q * 8];
            z = __builtin_amdgcn_mfma_f32_16x16x32_bf16(aq0, bk0, z, 0, 0, 0);
            z = __builtin_amdgcn_mfma_f32_16x16x32_bf16(aq1, bk1, z, 0, 0, 0);
            accS[nt] = z;
        }
        bool diag = (kt == qt);
#pragma unroll
        for (int nt = 0; nt < 4; ++nt)
#pragma unroll
            for (int r = 0; r < 4; ++r) {
                float s = accS[nt][r];
                if (diag) {
                    int key = nt * 16 + m16;
                    int qi = w * 16 + q * 4 + r;
                    if (key > qi) s = -__builtin_inff();
                }
                float pv = __builtin_amdgcn_exp2f(s);
                lrun[r] += pv;
                sP[w][(q * 4 + r) * SL + nt * 16 + m16] = f2bf(pv);
            }
        // no barrier: sP[w] wave-private; in-wave DS ordering handles RAW/WAR
        short8 ap0 = *(const short8*)&sP[w][m16 * SL + q * 8];
        short8 ap1 = *(const short8*)&sP[w][m16 * SL + 32 + q * 8];
#pragma unroll
        for (int nt = 0; nt < 4; ++nt) {
            short8 bv0 = *(const short8*)&sV[(nt * 16 + m16) * SL + q * 8];
            short8 bv1 = *(const short8*)&sV[(nt * 16 + m16) * SL + 32 + q * 8];
            accO[nt] = __builtin_amdgcn_mfma_f32_16x16x32_bf16(ap0, bv0, accO[nt], 0, 0, 0);
            accO[nt] = __builtin_amdgcn_mfma_f32_16x16x32_bf16(ap1, bv1, accO[nt], 0, 0, 0);
        }
    };

    for (int kt = 0; kt <= qtA; ++kt) {
        int kBase = kt * 64;
        __syncthreads();
#pragma unroll
        for (int it = 0; it < 2; ++it) {
            int row = cK + it * 32;
            *(float4*)&sK[row * SL + c8 * 8] =
                *(const float4*)(kbase + (size_t)(kBase + row) * 2048 + c8 * 8);
            *(float4*)&sV[row * SL + c8 * 8] =
                *(const float4*)(vbase + (size_t)row * 2048 + kBase + c8 * 8);
        }
        __syncthreads();

        process(aqA0, aqA1, lrunA, accOA, qtA, kt);
        if (kt <= qtB) process(aqB0, aqB1, lrunB, accOB, qtB, kt);
    }

    // end-of-kernel l reductions (16 lanes sharing each row differ in m16 bits)
#pragma unroll
    for (int r = 0; r < 4; ++r) {
        float la = lrunA[r], lb = lrunB[r];
        la += __shfl_xor(la, 1); lb += __shfl_xor(lb, 1);
        la += __shfl_xor(la, 2); lb += __shfl_xor(lb, 2);
        la += __shfl_xor(la, 4); lb += __shfl_xor(lb, 4);
        la += __shfl_xor(la, 8); lb += __shfl_xor(lb, 8);
        lrunA[r] = 1.0f / la; lrunB[r] = 1.0f / lb;
    }
#pragma unroll
    for (int nt = 0; nt < 4; ++nt)
#pragma unroll
        for (int r = 0; r < 4; ++r) {
            int col = h * 64 + nt * 16 + m16;
            O[(size_t)(b * 2048 + qtA * 64 + w * 16 + q * 4 + r) * 2048 + col] =
                f2bf(accOA[nt][r] * lrunA[r]);
            O[(size_t)(b * 2048 + qtB * 64 + w * 16 + q * 4 + r) * 2048 + col] =
                f2bf(accOB[nt][r] * lrunB[r]);
        }
}

// ---------------- host launcher ----------------
extern "C" void kernel_launch(void* const* d_in, const int* in_sizes, int n_in,
                              void* d_out, int out_size, void* d_ws, size_t ws_size,
                              hipStream_t stream) {
    const float* hs = (const float*)d_in[0];   // (2,2048,2048)
    const float* sk = (const float*)d_in[1];   // (2,2048,32,64)
    const float* sv = (const float*)d_in[2];   // (2,2048,32,64)
    const float* wq = (const float*)d_in[3];   // (2048,2048)
    const float* wo = (const float*)d_in[4];   // (2048,2048)
    float* out = (float*)d_out;

    char* ws = (char*)d_ws;
    unsigned short* hid_b = (unsigned short*)(ws);                              // 16 MiB
    unsigned short* wq_b  = (unsigned short*)(ws + ((size_t)16 << 20));         //  8 MiB
    unsigned short* wo_b  = (unsigned short*)(ws + ((size_t)24 << 20));         //  8 MiB
    unsigned short* k_b   = (unsigned short*)(ws + ((size_t)32 << 20));         // 16 MiB
    unsigned short* vt_b  = (unsigned short*)(ws + ((size_t)48 << 20));         // 16 MiB
    unsigned short* q_b   = (unsigned short*)(ws + ((size_t)64 << 20));         // 16 MiB
    unsigned short* o_b   = (unsigned short*)(ws + ((size_t)80 << 20));         // 16 MiB

    cvt_all<<<24576, 256, 0, stream>>>(hs, sk, wq, wo, hid_b, k_b, wq_b, wo_b);
    transpose_v<<<dim3(32, 64), 256, 0, stream>>>(sv, vt_b);
    gemm_bt<true><<<dim3(32, 16), 256, 0, stream>>>(hid_b, wq_b, (void*)q_b, 4096, 2048, 2048);
    attn<<<1024, 256, 0, stream>>>(q_b, k_b, vt_b, o_b);
    gemm_bt<false><<<dim3(32, 16), 256, 0, stream>>>(o_b, wo_b, (void*)out, 4096, 2048, 2048);
}

// Round 4
// 329.526 us; speedup vs baseline: 1.2392x; 1.2392x over previous
//
#include <hip/hip_runtime.h>
#include <stdint.h>

typedef short short8 __attribute__((ext_vector_type(8)));
typedef float f32x4 __attribute__((ext_vector_type(4)));

// 0.125 (1/sqrt(64)) * log2(e): fold softmax scale + exp2-domain into Q.
#define QSCALE 0.1803368801111137f
// log2(10000)/32
#define FREQC 0.4152410118609203f

__device__ __forceinline__ float bf2f(unsigned short u) {
    union { unsigned int i; float f; } x; x.i = ((unsigned int)u) << 16; return x.f;
}
__device__ __forceinline__ unsigned short f2bf(float f) {
    union { float f; unsigned int i; } x; x.f = f;
    unsigned int i = x.i;
    unsigned int r = i + 0x7FFFu + ((i >> 16) & 1u);   // RNE
    return (unsigned short)(r >> 16);
}

// async global->LDS, 16B/lane. HW dest = wave-uniform base + lane*16.
#define GLDS16(g, l) \
    __builtin_amdgcn_global_load_lds((const __attribute__((address_space(1))) void*)(g), \
                                     (__attribute__((address_space(3))) void*)(l), 16, 0, 0)

// ---------------- fused fp32 -> bf16 convert for all 4 arrays ----------------
__global__ void cvt_all(const float* __restrict__ hs, const float* __restrict__ k,
                        const float* __restrict__ wq, const float* __restrict__ wo,
                        unsigned short* __restrict__ hs_b, unsigned short* __restrict__ k_b,
                        unsigned short* __restrict__ wq_b, unsigned short* __restrict__ wo_b) {
    int blk = blockIdx.x;
    const float* in; unsigned short* out; int i;
    if (blk < 8192)        { in = hs; out = hs_b; i = blk * 256 + threadIdx.x; }
    else if (blk < 16384)  { in = k;  out = k_b;  i = (blk - 8192) * 256 + threadIdx.x; }
    else if (blk < 20480)  { in = wq; out = wq_b; i = (blk - 16384) * 256 + threadIdx.x; }
    else                   { in = wo; out = wo_b; i = (blk - 20480) * 256 + threadIdx.x; }
    float4 v = ((const float4*)in)[i];
    ushort4 o;
    o.x = f2bf(v.x); o.y = f2bf(v.y); o.z = f2bf(v.z); o.w = f2bf(v.w);
    ((ushort4*)out)[i] = o;
}

// ---------------- V: (B,T,H,D) f32 -> (B,H,D,T) bf16 ----------------
__global__ __launch_bounds__(256) void transpose_v(const float* __restrict__ V, unsigned short* __restrict__ Vt) {
    __shared__ float s[64 * 65];
    int t0 = blockIdx.x * 64;
    int bh = blockIdx.y;           // b*32 + h
    int b = bh >> 5, h = bh & 31;
    int tid = threadIdx.x;
#pragma unroll
    for (int it = 0; it < 4; ++it) {
        int c = tid + it * 256;
        int t = c >> 4;
        int d0 = (c & 15) * 4;
        float4 v = *(const float4*)(V + (size_t)(((b * 2048 + t0 + t) * 32 + h)) * 64 + d0);
        s[t * 65 + d0 + 0] = v.x; s[t * 65 + d0 + 1] = v.y;
        s[t * 65 + d0 + 2] = v.z; s[t * 65 + d0 + 3] = v.w;
    }
    __syncthreads();
#pragma unroll
    for (int it = 0; it < 2; ++it) {
        int c = tid + it * 256;
        int d = c >> 3;
        int tt = (c & 7) * 8;
        short8 pk;
#pragma unroll
        for (int j = 0; j < 8; ++j) pk[j] = (short)f2bf(s[(tt + j) * 65 + d]);
        *(short8*)(Vt + (size_t)(bh * 64 + d) * 2048 + t0 + tt) = pk;
    }
}

// ---------------- bf16 GEMM, C = A * B^T; BK=64, XOR-swizzled LDS ----------------
template <bool BF16_OUT>
__global__ __launch_bounds__(256) void gemm_bt(
    const unsigned short* __restrict__ A,   // M x K bf16
    const unsigned short* __restrict__ B,   // N x K bf16
    void* __restrict__ Cout,                // M x N
    int M, int N, int K)
{
    __shared__ __align__(16) unsigned short lA[128 * 64];
    __shared__ __align__(16) unsigned short lB[128 * 64];
    int tid = threadIdx.x, lane = tid & 63, wave = tid >> 6;
    int wm = (wave >> 1) * 64, wn = (wave & 1) * 64;
    int m16 = lane & 15, q = lane >> 4;
    int rowBase = blockIdx.x * 128, colBase = blockIdx.y * 128;
    f32x4 acc[4][4] = {};

    int sr = lane >> 3;            // 0..7: row within 8-row group
    int g  = (lane & 7) ^ sr;      // swizzled k-group
    const unsigned short* gAp = A + (size_t)(rowBase + wave * 32 + sr) * K + g * 8;
    const unsigned short* gBp = B + (size_t)(colBase + wave * 32 + sr) * K + g * 8;
    unsigned short* lAd = &lA[(wave * 32) * 64];
    unsigned short* lBd = &lB[(wave * 32) * 64];

    for (int k0 = 0; k0 < K; k0 += 64) {
        __syncthreads();
#pragma unroll
        for (int i = 0; i < 4; ++i) {
            GLDS16(gAp + (size_t)(8 * i) * K + k0, lAd + (8 * i) * 64);
            GLDS16(gBp + (size_t)(8 * i) * K + k0, lBd + (8 * i) * 64);
        }
        __syncthreads();
#pragma unroll
        for (int kk = 0; kk < 2; ++kk) {
            short8 af[4], bfr[4];
#pragma unroll
            for (int i = 0; i < 4; ++i) {
                int RA = wm + i * 16 + m16;
                af[i]  = *(const short8*)&lA[RA * 64 + (((kk * 4 + q) ^ (RA & 7)) * 8)];
                int RB = wn + i * 16 + m16;
                bfr[i] = *(const short8*)&lB[RB * 64 + (((kk * 4 + q) ^ (RB & 7)) * 8)];
            }
#pragma unroll
            for (int i = 0; i < 4; ++i)
#pragma unroll
                for (int jn = 0; jn < 4; ++jn)
                    acc[i][jn] = __builtin_amdgcn_mfma_f32_16x16x32_bf16(af[i], bfr[jn], acc[i][jn], 0, 0, 0);
        }
    }
#pragma unroll
    for (int i = 0; i < 4; ++i)
#pragma unroll
        for (int jn = 0; jn < 4; ++jn)
#pragma unroll
            for (int r = 0; r < 4; ++r) {
                int row = rowBase + wm + i * 16 + q * 4 + r;   // C row = quad*4+reg
                int col = colBase + wn + jn * 16 + m16;        // C col = lane&15
                float v = acc[i][jn][r];
                if (BF16_OUT) ((unsigned short*)Cout)[(size_t)row * N + col] = f2bf(v);
                else          ((float*)Cout)[(size_t)row * N + col] = v;
            }
}

// ---------------- flash attention (causal), paired Q-tiles, RoPE fused ----------------
// Block = (pair p, bh): Q-tiles qtA=31-p, qtB=p -> exactly 33 tile-computations
// per block; shared K/V staging. flat%8 == bh%8 -> (b,h) pinned to one XCD.
// PROCESS is a macro over NAMED local arrays (constant indices after unroll):
// lambda-with-pointer-params in R3 defeated mem2reg -> 680 MB scratch spill. Never again.
#define PROCESS(AQ0, AQ1, LRUN, ACCO, QT)                                          \
    do {                                                                           \
        bool diag = (kt == (QT));                                                  \
        _Pragma("unroll")                                                          \
        for (int nt = 0; nt < 4; ++nt) {                                           \
            f32x4 z = {0.f, 0.f, 0.f, 0.f};                                        \
            short8 bk0 = *(const short8*)&sK[(nt * 16 + m16) * SL + q * 8];        \
            short8 bk1 = *(const short8*)&sK[(nt * 16 + m16) * SL + 32 + q * 8];   \
            z = __builtin_amdgcn_mfma_f32_16x16x32_bf16(AQ0, bk0, z, 0, 0, 0);     \
            z = __builtin_amdgcn_mfma_f32_16x16x32_bf16(AQ1, bk1, z, 0, 0, 0);     \
            _Pragma("unroll")                                                      \
            for (int r = 0; r < 4; ++r) {                                          \
                float s = z[r];                                                    \
                if (diag) {                                                        \
                    int key = nt * 16 + m16;                                       \
                    int qi = w * 16 + q * 4 + r;                                   \
                    if (key > qi) s = -__builtin_inff();                           \
                }                                                                  \
                float pv = __builtin_amdgcn_exp2f(s);                              \
                LRUN[r] += pv;                                                     \
                sP[w][(q * 4 + r) * SL + nt * 16 + m16] = f2bf(pv);                \
            }                                                                      \
        }                                                                          \
        short8 ap0 = *(const short8*)&sP[w][m16 * SL + q * 8];                     \
        short8 ap1 = *(const short8*)&sP[w][m16 * SL + 32 + q * 8];                \
        _Pragma("unroll")                                                          \
        for (int nt = 0; nt < 4; ++nt) {                                           \
            short8 bv0 = *(const short8*)&sV[(nt * 16 + m16) * SL + q * 8];        \
            short8 bv1 = *(const short8*)&sV[(nt * 16 + m16) * SL + 32 + q * 8];   \
            ACCO[nt] = __builtin_amdgcn_mfma_f32_16x16x32_bf16(ap0, bv0, ACCO[nt], 0, 0, 0); \
            ACCO[nt] = __builtin_amdgcn_mfma_f32_16x16x32_bf16(ap1, bv1, ACCO[nt], 0, 0, 0); \
        }                                                                          \
    } while (0)

__global__ __launch_bounds__(256, 3) void attn(
    const unsigned short* __restrict__ Q,   // (B*T) x 2048, raw gemm1 output (no rope)
    const unsigned short* __restrict__ Kb,  // (B*T) x 2048
    const unsigned short* __restrict__ Vt,  // (B*H*64) x 2048  (d-major)
    unsigned short* __restrict__ O)         // (B*T) x 2048
{
    const int SL = 72;  // stride 36 dwords -> 2-way bank aliasing only (free)
    __shared__ __align__(16) unsigned short sK[64 * SL];
    __shared__ __align__(16) unsigned short sV[64 * SL];     // rows = d, cols = key
    __shared__ __align__(16) unsigned short sP[4][16 * SL];
    int tid = threadIdx.x, lane = tid & 63, w = tid >> 6;
    int m16 = lane & 15, q = lane >> 4;
    int flat = blockIdx.x;
    int bh = flat & 63, p = flat >> 6;
    int b = bh >> 5, h = bh & 31;
    int qtA = 31 - p, qtB = p;

    // Q fragments for both tiles: load, RoPE (interleaved pairs are frag-local), scale.
    short8 aqA0, aqA1, aqB0, aqB1;
    {
        int tA = qtA * 64 + w * 16 + m16;
        int tB = qtB * 64 + w * 16 + m16;
        const unsigned short* rowA = Q + (size_t)(b * 2048 + tA) * 2048 + h * 64 + q * 8;
        const unsigned short* rowB = Q + (size_t)(b * 2048 + tB) * 2048 + h * 64 + q * 8;
        short8 a0 = *(const short8*)rowA, a1 = *(const short8*)(rowA + 32);
        short8 b0 = *(const short8*)rowB, b1 = *(const short8*)(rowB + 32);
        float tfA = (float)tA, tfB = (float)tB;
#pragma unroll
        for (int j = 0; j < 4; ++j) {
            float inv0 = __builtin_amdgcn_exp2f(-FREQC * (float)(q * 4 + j));
            float inv1 = __builtin_amdgcn_exp2f(-FREQC * (float)(16 + q * 4 + j));
            float cA0 = __cosf(tfA * inv0), sA0 = __sinf(tfA * inv0);
            float cA1 = __cosf(tfA * inv1), sA1 = __sinf(tfA * inv1);
            float cB0 = __cosf(tfB * inv0), sB0 = __sinf(tfB * inv0);
            float cB1 = __cosf(tfB * inv1), sB1 = __sinf(tfB * inv1);
            float x1, x2;
            x1 = bf2f((unsigned short)a0[2 * j]); x2 = bf2f((unsigned short)a0[2 * j + 1]);
            aqA0[2 * j]     = (short)f2bf((x1 * cA0 - x2 * sA0) * QSCALE);
            aqA0[2 * j + 1] = (short)f2bf((x1 * sA0 + x2 * cA0) * QSCALE);
            x1 = bf2f((unsigned short)a1[2 * j]); x2 = bf2f((unsigned short)a1[2 * j + 1]);
            aqA1[2 * j]     = (short)f2bf((x1 * cA1 - x2 * sA1) * QSCALE);
            aqA1[2 * j + 1] = (short)f2bf((x1 * sA1 + x2 * cA1) * QSCALE);
            x1 = bf2f((unsigned short)b0[2 * j]); x2 = bf2f((unsigned short)b0[2 * j + 1]);
            aqB0[2 * j]     = (short)f2bf((x1 * cB0 - x2 * sB0) * QSCALE);
            aqB0[2 * j + 1] = (short)f2bf((x1 * sB0 + x2 * cB0) * QSCALE);
            x1 = bf2f((unsigned short)b1[2 * j]); x2 = bf2f((unsigned short)b1[2 * j + 1]);
            aqB1[2 * j]     = (short)f2bf((x1 * cB1 - x2 * sB1) * QSCALE);
            aqB1[2 * j + 1] = (short)f2bf((x1 * sB1 + x2 * cB1) * QSCALE);
        }
    }

    float lrunA[4] = {0.f, 0.f, 0.f, 0.f}, lrunB[4] = {0.f, 0.f, 0.f, 0.f};
    f32x4 accOA[4], accOB[4];
#pragma unroll
    for (int nt = 0; nt < 4; ++nt) {
        f32x4 z = {0.f, 0.f, 0.f, 0.f};
        accOA[nt] = z; accOB[nt] = z;
    }

    int cK = tid >> 3, c8 = tid & 7;
    const unsigned short* kbase = Kb + (size_t)(b * 2048) * 2048 + h * 64;
    const unsigned short* vbase = Vt + (size_t)((b * 32 + h) * 64) * 2048;

    for (int kt = 0; kt <= qtA; ++kt) {
        int kBase = kt * 64;
        __syncthreads();
#pragma unroll
        for (int it = 0; it < 2; ++it) {
            int row = cK + it * 32;
            *(float4*)&sK[row * SL + c8 * 8] =
                *(const float4*)(kbase + (size_t)(kBase + row) * 2048 + c8 * 8);
            *(float4*)&sV[row * SL + c8 * 8] =
                *(const float4*)(vbase + (size_t)row * 2048 + kBase + c8 * 8);
        }
        __syncthreads();

        PROCESS(aqA0, aqA1, lrunA, accOA, qtA);
        if (kt <= qtB) PROCESS(aqB0, aqB1, lrunB, accOB, qtB);
    }

    // end-of-kernel l reductions (16 lanes sharing each row differ in m16 bits)
#pragma unroll
    for (int r = 0; r < 4; ++r) {
        float la = lrunA[r], lb = lrunB[r];
        la += __shfl_xor(la, 1); lb += __shfl_xor(lb, 1);
        la += __shfl_xor(la, 2); lb += __shfl_xor(lb, 2);
        la += __shfl_xor(la, 4); lb += __shfl_xor(lb, 4);
        la += __shfl_xor(la, 8); lb += __shfl_xor(lb, 8);
        lrunA[r] = 1.0f / la; lrunB[r] = 1.0f / lb;
    }
#pragma unroll
    for (int nt = 0; nt < 4; ++nt)
#pragma unroll
        for (int r = 0; r < 4; ++r) {
            int col = h * 64 + nt * 16 + m16;
            O[(size_t)(b * 2048 + qtA * 64 + w * 16 + q * 4 + r) * 2048 + col] =
                f2bf(accOA[nt][r] * lrunA[r]);
            O[(size_t)(b * 2048 + qtB * 64 + w * 16 + q * 4 + r) * 2048 + col] =
                f2bf(accOB[nt][r] * lrunB[r]);
        }
}

// ---------------- host launcher ----------------
extern "C" void kernel_launch(void* const* d_in, const int* in_sizes, int n_in,
                              void* d_out, int out_size, void* d_ws, size_t ws_size,
                              hipStream_t stream) {
    const float* hs = (const float*)d_in[0];   // (2,2048,2048)
    const float* sk = (const float*)d_in[1];   // (2,2048,32,64)
    const float* sv = (const float*)d_in[2];   // (2,2048,32,64)
    const float* wq = (const float*)d_in[3];   // (2048,2048)
    const float* wo = (const float*)d_in[4];   // (2048,2048)
    float* out = (float*)d_out;

    char* ws = (char*)d_ws;
    unsigned short* hid_b = (unsigned short*)(ws);                              // 16 MiB
    unsigned short* wq_b  = (unsigned short*)(ws + ((size_t)16 << 20));         //  8 MiB
    unsigned short* wo_b  = (unsigned short*)(ws + ((size_t)24 << 20));         //  8 MiB
    unsigned short* k_b   = (unsigned short*)(ws + ((size_t)32 << 20));         // 16 MiB
    unsigned short* vt_b  = (unsigned short*)(ws + ((size_t)48 << 20));         // 16 MiB
    unsigned short* q_b   = (unsigned short*)(ws + ((size_t)64 << 20));         // 16 MiB
    unsigned short* o_b   = (unsigned short*)(ws + ((size_t)80 << 20));         // 16 MiB

    cvt_all<<<24576, 256, 0, stream>>>(hs, sk, wq, wo, hid_b, k_b, wq_b, wo_b);
    transpose_v<<<dim3(32, 64), 256, 0, stream>>>(sv, vt_b);
    gemm_bt<true><<<dim3(32, 16), 256, 0, stream>>>(hid_b, wq_b, (void*)q_b, 4096, 2048, 2048);
    attn<<<1024, 256, 0, stream>>>(q_b, k_b, vt_b, o_b);
    gemm_bt<false><<<dim3(32, 16), 256, 0, stream>>>(o_b, wo_b, (void*)out, 4096, 2048, 2048);
}